// Round 1
// baseline (2713.046 us; speedup 1.0000x reference)
//
#include <hip/hip_runtime.h>
#include <cstdint>
#include <cstddef>

// Problem constants (match reference)
#define FEAT 128          // IN_DIM == HID
#define NLAYERS 3
#define EPS 1e-5f

// ---------------------------------------------------------------------------
// CSR build: in-degree histogram -> exclusive scan -> fill (by target node)
// ---------------------------------------------------------------------------

__global__ void hist_k(const int* __restrict__ col, int* __restrict__ hist, int E) {
  int e = blockIdx.x * blockDim.x + threadIdx.x;
  if (e < E) atomicAdd(&hist[col[e]], 1);
}

__global__ void scan1(const int* __restrict__ hist, int* __restrict__ bsum, int N) {
  __shared__ int s[256];
  int t = threadIdx.x;
  int n = blockIdx.x * 256 + t;
  s[t] = (n < N) ? hist[n] : 0;
  __syncthreads();
  for (int o = 128; o > 0; o >>= 1) {
    if (t < o) s[t] += s[t + o];
    __syncthreads();
  }
  if (t == 0) bsum[blockIdx.x] = s[0];
}

__global__ void scan2(int* __restrict__ bsum, int nb) {
  // single block, blockDim = 512, nb <= 512
  __shared__ int s[512];
  int t = threadIdx.x;
  int v = (t < nb) ? bsum[t] : 0;
  s[t] = v;
  __syncthreads();
  for (int o = 1; o < 512; o <<= 1) {
    int add = (t >= o) ? s[t - o] : 0;
    __syncthreads();
    s[t] += add;
    __syncthreads();
  }
  if (t < nb) bsum[t] = s[t] - v;  // exclusive
}

__global__ void scan3(const int* __restrict__ hist, const int* __restrict__ bsum,
                      int* __restrict__ rowstart, int* __restrict__ cursor,
                      float* __restrict__ dis, int N, int E) {
  __shared__ int s[256];
  int t = threadIdx.x;
  int n = blockIdx.x * 256 + t;
  int v = (n < N) ? hist[n] : 0;
  s[t] = v;
  __syncthreads();
  for (int o = 1; o < 256; o <<= 1) {
    int add = (t >= o) ? s[t - o] : 0;
    __syncthreads();
    s[t] += add;
    __syncthreads();
  }
  if (n < N) {
    int excl = bsum[blockIdx.x] + s[t] - v;
    rowstart[n] = excl;
    cursor[n] = excl;
    // deg = in-degree + 1 (self loop); dis = rsqrt(deg)
    dis[n] = rsqrtf((float)(v + 1));
    if (n == N - 1) rowstart[N] = E;
  }
}

__global__ void fill_k(const int* __restrict__ row, const int* __restrict__ col,
                       int* __restrict__ cursor, int* __restrict__ csrc, int E) {
  int e = blockIdx.x * blockDim.x + threadIdx.x;
  if (e >= E) return;
  int c = col[e];
  int pos = atomicAdd(&cursor[c], 1);
  csrc[pos] = row[e];
}

// ---------------------------------------------------------------------------
// Graph boundaries from sorted batch vector (start[g] per graph, start[G]=N)
// ---------------------------------------------------------------------------
__global__ void boundaries_k(const int* __restrict__ batch, int* __restrict__ gstart,
                             int N, int G) {
  int n = blockIdx.x * blockDim.x + threadIdx.x;
  if (n >= N) return;
  int b = batch[n];
  int prev = (n == 0) ? -1 : batch[n - 1];
  for (int g = prev + 1; g <= b; ++g) gstart[g] = n;
  if (n == N - 1) {
    for (int g = b + 1; g <= G; ++g) gstart[g] = N;
  }
}

// ---------------------------------------------------------------------------
// Precompute fused BN affine per layer: y = s*x + t  where x = agg (pre-bias)
// s = gamma * rsqrt(var+eps); t = (b_conv - mean)*s + beta
// b_conv layout (L,P,64) flattens to (L,128) over features.
// ---------------------------------------------------------------------------
__global__ void bnprep_k(const float* __restrict__ bconv, const float* __restrict__ gamma,
                         const float* __restrict__ beta, const float* __restrict__ mean,
                         const float* __restrict__ var, float* __restrict__ bns,
                         float* __restrict__ bnt) {
  int l = blockIdx.x;
  int f = threadIdx.x;
  int i = l * FEAT + f;
  float s = gamma[i] * rsqrtf(var[i] + EPS);
  bns[i] = s;
  bnt[i] = (bconv[i] - mean[i]) * s + beta[i];
}

// ---------------------------------------------------------------------------
// xw = h @ blockdiag(W[l,0], W[l,1]) : [N,128] x (2 of 64x64)
// Tile: 64 nodes x 128 outputs per block (256 thr), 4x4 register tile/thread.
// ---------------------------------------------------------------------------
__global__ __launch_bounds__(256) void xw_k(const float* __restrict__ h,
                                            const float* __restrict__ W,  // + l*8192
                                            float* __restrict__ xw, int N) {
  __shared__ float hT[64 * 68];  // [k][n], row stride 68 floats (272B, 16B-aligned)
  __shared__ float Ws[64 * 64];  // [k][j]
  const int t = threadIdx.x;
  const int a = t >> 4;   // node-quad 0..15
  const int b = t & 15;   // out-quad  0..15
  const int base = blockIdx.x * 64;

  for (int p = 0; p < 2; ++p) {
    // stage W[p] (4096 floats, contiguous)
    {
      const float4* src = (const float4*)(W + p * 4096);
      float4* dst = (float4*)Ws;
#pragma unroll
      for (int r = 0; r < 4; ++r) dst[r * 256 + t] = src[r * 256 + t];
    }
    // stage h tile transposed: hT[k][n] = h[base+n][p*64+k]
#pragma unroll
    for (int r = 0; r < 4; ++r) {
      int qid = r * 256 + t;   // 0..1023
      int n = qid >> 4;        // 0..63
      int q = qid & 15;        // k-quad
      float4 v = make_float4(0.f, 0.f, 0.f, 0.f);
      int node = base + n;
      if (node < N) v = *(const float4*)(h + (size_t)node * FEAT + p * 64 + q * 4);
      hT[(q * 4 + 0) * 68 + n] = v.x;
      hT[(q * 4 + 1) * 68 + n] = v.y;
      hT[(q * 4 + 2) * 68 + n] = v.z;
      hT[(q * 4 + 3) * 68 + n] = v.w;
    }
    __syncthreads();

    float acc[4][4];
#pragma unroll
    for (int i = 0; i < 4; ++i)
#pragma unroll
      for (int j = 0; j < 4; ++j) acc[i][j] = 0.f;

#pragma unroll 8
    for (int k = 0; k < 64; ++k) {
      float4 hv = *(const float4*)(hT + k * 68 + a * 4);
      float4 wv = *(const float4*)(Ws + k * 64 + b * 4);
      acc[0][0] += hv.x * wv.x; acc[0][1] += hv.x * wv.y; acc[0][2] += hv.x * wv.z; acc[0][3] += hv.x * wv.w;
      acc[1][0] += hv.y * wv.x; acc[1][1] += hv.y * wv.y; acc[1][2] += hv.y * wv.z; acc[1][3] += hv.y * wv.w;
      acc[2][0] += hv.z * wv.x; acc[2][1] += hv.z * wv.y; acc[2][2] += hv.z * wv.z; acc[2][3] += hv.z * wv.w;
      acc[3][0] += hv.w * wv.x; acc[3][1] += hv.w * wv.y; acc[3][2] += hv.w * wv.z; acc[3][3] += hv.w * wv.w;
    }

#pragma unroll
    for (int i = 0; i < 4; ++i) {
      int node = base + a * 4 + i;
      if (node < N) {
        *(float4*)(xw + (size_t)node * FEAT + p * 64 + b * 4) =
            make_float4(acc[i][0], acc[i][1], acc[i][2], acc[i][3]);
      }
    }
    __syncthreads();
  }
}

// ---------------------------------------------------------------------------
// Gather + self-loop + bias/BN/ReLU fused. One wave per node; lane holds 2
// consecutive features (float2 -> 512B coalesced row reads).
// agg[i] = dis[i] * ( sum_{e in-edges} dis[src]*xw[src] + dis[i]*xw[i] )
// h_out  = relu(agg*s + t)
// ---------------------------------------------------------------------------
__global__ __launch_bounds__(256) void gather_k(const float* __restrict__ xw,
                                                const float* __restrict__ dis,
                                                const int* __restrict__ rowstart,
                                                const int* __restrict__ csrc,
                                                const float* __restrict__ bns,  // + l*128
                                                const float* __restrict__ bnt,  // + l*128
                                                float* __restrict__ hout, int N) {
  int wid = (blockIdx.x * blockDim.x + threadIdx.x) >> 6;  // node id
  if (wid >= N) return;
  int lane = threadIdx.x & 63;
  int f = lane * 2;
  int e0 = rowstart[wid];
  int e1 = rowstart[wid + 1];
  float di = dis[wid];

  float2 xs = *(const float2*)(xw + (size_t)wid * FEAT + f);
  float ax = xs.x * di;
  float ay = xs.y * di;
  for (int e = e0; e < e1; ++e) {
    int s = csrc[e];
    float ds = dis[s];
    float2 v = *(const float2*)(xw + (size_t)s * FEAT + f);
    ax += v.x * ds;
    ay += v.y * ds;
  }
  ax *= di;
  ay *= di;
  float2 r;
  r.x = fmaxf(ax * bns[f] + bnt[f], 0.f);
  r.y = fmaxf(ay * bns[f + 1] + bnt[f + 1], 0.f);
  *(float2*)(hout + (size_t)wid * FEAT + f) = r;
}

// ---------------------------------------------------------------------------
// Per-graph feature sums for one layer segment of the JK concat.
// grid (G, 2), block 64; no atomics (each (g,f) owned by one thread).
// ---------------------------------------------------------------------------
__global__ void pool_k(const float* __restrict__ h, const int* __restrict__ gstart,
                       float* __restrict__ sums, int layer) {
  int g = blockIdx.x;
  int f = blockIdx.y * 64 + threadIdx.x;
  int s0 = gstart[g];
  int s1 = gstart[g + 1];
  float acc = 0.f;
  for (int n = s0; n < s1; ++n) acc += h[(size_t)n * FEAT + f];
  sums[g * (NLAYERS * FEAT) + layer * FEAT + f] = acc;
}

// ---------------------------------------------------------------------------
// Head: pooled = sums/cnt; z1 = relu(pooled@W1+b1); z2 = z1@W2+b2; log_softmax.
// grid G blocks, 128 threads.
// ---------------------------------------------------------------------------
__global__ __launch_bounds__(128) void head_k(const float* __restrict__ sums,
                                              const int* __restrict__ gstart,
                                              const float* __restrict__ W1,
                                              const float* __restrict__ b1,
                                              const float* __restrict__ W2,
                                              const float* __restrict__ b2,
                                              float* __restrict__ out) {
  __shared__ float pooled[NLAYERS * FEAT];
  __shared__ float z1[FEAT];
  __shared__ float z2[2];
  int g = blockIdx.x;
  int t = threadIdx.x;
  float cnt = (float)(gstart[g + 1] - gstart[g]);
  float inv = 1.f / fmaxf(cnt, 1.f);
  for (int k = t; k < NLAYERS * FEAT; k += 128) pooled[k] = sums[g * (NLAYERS * FEAT) + k] * inv;
  __syncthreads();
  float acc = b1[t];
  for (int k = 0; k < NLAYERS * FEAT; ++k) acc += pooled[k] * W1[k * FEAT + t];
  z1[t] = fmaxf(acc, 0.f);
  __syncthreads();
  if (t < 2) {
    float a = b2[t];
    for (int j = 0; j < FEAT; ++j) a += z1[j] * W2[j * 2 + t];
    z2[t] = a;
  }
  __syncthreads();
  if (t < 2) {
    float m = fmaxf(z2[0], z2[1]);
    float lse = m + logf(expf(z2[0] - m) + expf(z2[1] - m));
    out[g * 2 + t] = z2[t] - lse;
  }
}

// ---------------------------------------------------------------------------

extern "C" void kernel_launch(void* const* d_in, const int* in_sizes, int n_in,
                              void* d_out, int out_size, void* d_ws, size_t ws_size,
                              hipStream_t stream) {
  const float* x    = (const float*)d_in[0];
  const int*   ei   = (const int*)d_in[1];   // [2, E]
  const int*   batch= (const int*)d_in[2];   // [N]
  const float* Wc   = (const float*)d_in[3]; // [3,2,64,64]
  const float* bc   = (const float*)d_in[4]; // [3,2,64] == [3,128]
  const float* gam  = (const float*)d_in[5];
  const float* bet  = (const float*)d_in[6];
  const float* mu   = (const float*)d_in[7];
  const float* var  = (const float*)d_in[8];
  const float* W1   = (const float*)d_in[9];  // [384,128]
  const float* b1   = (const float*)d_in[10]; // [128]
  const float* W2   = (const float*)d_in[11]; // [128,2]
  const float* b2   = (const float*)d_in[12]; // [2]
  float* out = (float*)d_out;

  const int N = in_sizes[0] / FEAT;
  const int E = in_sizes[1] / 2;
  const int G = out_size / 2;

  const int* row = ei;
  const int* col = ei + E;

  // workspace carve (256B aligned)
  char* p = (char*)d_ws;
  auto alloc = [&](size_t bytes) -> void* {
    void* q = (void*)p;
    p += (bytes + 255) & ~(size_t)255;
    return q;
  };
  int*   hist     = (int*)alloc((size_t)N * 4);
  float* dis      = (float*)alloc((size_t)N * 4);
  int*   rowstart = (int*)alloc((size_t)(N + 1) * 4);
  int*   cursor   = (int*)alloc((size_t)N * 4);
  int*   csrc     = (int*)alloc((size_t)E * 4);
  int*   bsum     = (int*)alloc(1024 * 4);
  int*   gstart   = (int*)alloc(1024 * 4);
  float* bns      = (float*)alloc(NLAYERS * FEAT * 4);
  float* bnt      = (float*)alloc(NLAYERS * FEAT * 4);
  float* sums     = (float*)alloc((size_t)G * NLAYERS * FEAT * 4);
  float* bufA     = (float*)alloc((size_t)N * FEAT * 4);  // xw
  float* bufB     = (float*)alloc((size_t)N * FEAT * 4);  // h (post act)

  const int nbN = (N + 255) / 256;
  const int nbE = (E + 255) / 256;

  // CSR build
  hipMemsetAsync(hist, 0, (size_t)N * 4, stream);
  hist_k<<<nbE, 256, 0, stream>>>(col, hist, E);
  scan1<<<nbN, 256, 0, stream>>>(hist, bsum, N);
  scan2<<<1, 512, 0, stream>>>(bsum, nbN);
  scan3<<<nbN, 256, 0, stream>>>(hist, bsum, rowstart, cursor, dis, N, E);
  fill_k<<<nbE, 256, 0, stream>>>(row, col, cursor, csrc, E);

  // graph boundaries + fused BN params
  boundaries_k<<<nbN, 256, 0, stream>>>(batch, gstart, N, G);
  bnprep_k<<<NLAYERS, FEAT, 0, stream>>>(bc, gam, bet, mu, var, bns, bnt);

  // layers
  const int xwBlocks = (N + 63) / 64;
  const int gaBlocks = (N + 3) / 4;
  const float* hin = x;
  for (int l = 0; l < NLAYERS; ++l) {
    xw_k<<<xwBlocks, 256, 0, stream>>>(hin, Wc + (size_t)l * 8192, bufA, N);
    gather_k<<<gaBlocks, 256, 0, stream>>>(bufA, dis, rowstart, csrc,
                                           bns + l * FEAT, bnt + l * FEAT, bufB, N);
    pool_k<<<dim3(G, 2), 64, 0, stream>>>(bufB, gstart, sums, l);
    hin = bufB;
  }

  head_k<<<G, 128, 0, stream>>>(sums, gstart, W1, b1, W2, b2, out);
}

// Round 2
// 2372.906 us; speedup vs baseline: 1.1433x; 1.1433x over previous
//
#include <hip/hip_runtime.h>
#include <cstdint>
#include <cstddef>

// Problem constants (match reference)
#define FEAT 128          // IN_DIM == HID
#define NLAYERS 3
#define EPS 1e-5f

// ---------------------------------------------------------------------------
// CSR build: in-degree histogram -> exclusive scan -> fill (by target node)
// ---------------------------------------------------------------------------

__global__ void hist_k(const int* __restrict__ col, int* __restrict__ hist, int E) {
  int e = blockIdx.x * blockDim.x + threadIdx.x;
  if (e < E) atomicAdd(&hist[col[e]], 1);
}

__global__ void scan1(const int* __restrict__ hist, int* __restrict__ bsum, int N) {
  __shared__ int s[256];
  int t = threadIdx.x;
  int n = blockIdx.x * 256 + t;
  s[t] = (n < N) ? hist[n] : 0;
  __syncthreads();
  for (int o = 128; o > 0; o >>= 1) {
    if (t < o) s[t] += s[t + o];
    __syncthreads();
  }
  if (t == 0) bsum[blockIdx.x] = s[0];
}

__global__ void scan2(int* __restrict__ bsum, int nb) {
  // single block, blockDim = 512, nb <= 512
  __shared__ int s[512];
  int t = threadIdx.x;
  int v = (t < nb) ? bsum[t] : 0;
  s[t] = v;
  __syncthreads();
  for (int o = 1; o < 512; o <<= 1) {
    int add = (t >= o) ? s[t - o] : 0;
    __syncthreads();
    s[t] += add;
    __syncthreads();
  }
  if (t < nb) bsum[t] = s[t] - v;  // exclusive
}

__global__ void scan3(const int* __restrict__ hist, const int* __restrict__ bsum,
                      int* __restrict__ rowstart, int* __restrict__ cursor,
                      float* __restrict__ dis, int N, int E) {
  __shared__ int s[256];
  int t = threadIdx.x;
  int n = blockIdx.x * 256 + t;
  int v = (n < N) ? hist[n] : 0;
  s[t] = v;
  __syncthreads();
  for (int o = 1; o < 256; o <<= 1) {
    int add = (t >= o) ? s[t - o] : 0;
    __syncthreads();
    s[t] += add;
    __syncthreads();
  }
  if (n < N) {
    int excl = bsum[blockIdx.x] + s[t] - v;
    rowstart[n] = excl;
    cursor[n] = excl;
    // deg = in-degree + 1 (self loop); dis = rsqrt(deg)
    dis[n] = rsqrtf((float)(v + 1));
    if (n == N - 1) rowstart[N] = E;
  }
}

__global__ void fill_k(const int* __restrict__ row, const int* __restrict__ col,
                       int* __restrict__ cursor, int* __restrict__ csrc, int E) {
  int e = blockIdx.x * blockDim.x + threadIdx.x;
  if (e >= E) return;
  int c = col[e];
  int pos = atomicAdd(&cursor[c], 1);
  csrc[pos] = row[e];
}

// ---------------------------------------------------------------------------
// Graph boundaries from sorted batch vector (start[g] per graph, start[G]=N)
// ---------------------------------------------------------------------------
__global__ void boundaries_k(const int* __restrict__ batch, int* __restrict__ gstart,
                             int N, int G) {
  int n = blockIdx.x * blockDim.x + threadIdx.x;
  if (n >= N) return;
  int b = batch[n];
  int prev = (n == 0) ? -1 : batch[n - 1];
  for (int g = prev + 1; g <= b; ++g) gstart[g] = n;
  if (n == N - 1) {
    for (int g = b + 1; g <= G; ++g) gstart[g] = N;
  }
}

// ---------------------------------------------------------------------------
// Precompute fused BN affine per layer: y = s*x + t  where x = agg (pre-bias)
// s = gamma * rsqrt(var+eps); t = (b_conv - mean)*s + beta
// ---------------------------------------------------------------------------
__global__ void bnprep_k(const float* __restrict__ bconv, const float* __restrict__ gamma,
                         const float* __restrict__ beta, const float* __restrict__ mean,
                         const float* __restrict__ var, float* __restrict__ bns,
                         float* __restrict__ bnt) {
  int l = blockIdx.x;
  int f = threadIdx.x;
  int i = l * FEAT + f;
  float s = gamma[i] * rsqrtf(var[i] + EPS);
  bns[i] = s;
  bnt[i] = (bconv[i] - mean[i]) * s + beta[i];
}

// ---------------------------------------------------------------------------
// xs = dis[n] * (h @ blockdiag(W[l,0], W[l,1])) : pre-scaled by source norm.
// Tile: 64 nodes x 128 outputs per block (256 thr), 4x4 register tile/thread.
// ---------------------------------------------------------------------------
__global__ __launch_bounds__(256) void xw_k(const float* __restrict__ h,
                                            const float* __restrict__ W,  // + l*8192
                                            const float* __restrict__ dis,
                                            float* __restrict__ xs, int N) {
  __shared__ float hT[64 * 68];  // [k][n], row stride 68 floats (272B, 16B-aligned)
  __shared__ float Ws[64 * 64];  // [k][j]
  const int t = threadIdx.x;
  const int a = t >> 4;   // node-quad 0..15
  const int b = t & 15;   // out-quad  0..15
  const int base = blockIdx.x * 64;

  for (int p = 0; p < 2; ++p) {
    // stage W[p] (4096 floats, contiguous)
    {
      const float4* src = (const float4*)(W + p * 4096);
      float4* dst = (float4*)Ws;
#pragma unroll
      for (int r = 0; r < 4; ++r) dst[r * 256 + t] = src[r * 256 + t];
    }
    // stage h tile transposed: hT[k][n] = h[base+n][p*64+k]
#pragma unroll
    for (int r = 0; r < 4; ++r) {
      int qid = r * 256 + t;   // 0..1023
      int n = qid >> 4;        // 0..63
      int q = qid & 15;        // k-quad
      float4 v = make_float4(0.f, 0.f, 0.f, 0.f);
      int node = base + n;
      if (node < N) v = *(const float4*)(h + (size_t)node * FEAT + p * 64 + q * 4);
      hT[(q * 4 + 0) * 68 + n] = v.x;
      hT[(q * 4 + 1) * 68 + n] = v.y;
      hT[(q * 4 + 2) * 68 + n] = v.z;
      hT[(q * 4 + 3) * 68 + n] = v.w;
    }
    __syncthreads();

    float acc[4][4];
#pragma unroll
    for (int i = 0; i < 4; ++i)
#pragma unroll
      for (int j = 0; j < 4; ++j) acc[i][j] = 0.f;

#pragma unroll 8
    for (int k = 0; k < 64; ++k) {
      float4 hv = *(const float4*)(hT + k * 68 + a * 4);
      float4 wv = *(const float4*)(Ws + k * 64 + b * 4);
      acc[0][0] += hv.x * wv.x; acc[0][1] += hv.x * wv.y; acc[0][2] += hv.x * wv.z; acc[0][3] += hv.x * wv.w;
      acc[1][0] += hv.y * wv.x; acc[1][1] += hv.y * wv.y; acc[1][2] += hv.y * wv.z; acc[1][3] += hv.y * wv.w;
      acc[2][0] += hv.z * wv.x; acc[2][1] += hv.z * wv.y; acc[2][2] += hv.z * wv.z; acc[2][3] += hv.z * wv.w;
      acc[3][0] += hv.w * wv.x; acc[3][1] += hv.w * wv.y; acc[3][2] += hv.w * wv.z; acc[3][3] += hv.w * wv.w;
    }

#pragma unroll
    for (int i = 0; i < 4; ++i) {
      int node = base + a * 4 + i;
      if (node < N) {
        float d = dis[node];
        *(float4*)(xs + (size_t)node * FEAT + p * 64 + b * 4) =
            make_float4(acc[i][0] * d, acc[i][1] * d, acc[i][2] * d, acc[i][3] * d);
      }
    }
    __syncthreads();
  }
}

// ---------------------------------------------------------------------------
// Gather + self-loop + bias/BN/ReLU + pooled-sum fused. One wave per node;
// lane holds 2 consecutive features (float2 -> 512B coalesced row reads).
// xs is pre-scaled by dis[src], so:
//   agg[i] = dis[i] * ( sum_{in-edges} xs[src] + xs[i] )
//   h_out  = relu(agg*s + t);  sums[batch[i]] += h_out
// ---------------------------------------------------------------------------
__global__ __launch_bounds__(256) void gather_k(const float* __restrict__ xs,
                                                const float* __restrict__ dis,
                                                const int* __restrict__ rowstart,
                                                const int* __restrict__ csrc,
                                                const int* __restrict__ batch,
                                                const float* __restrict__ bns,  // + l*128
                                                const float* __restrict__ bnt,  // + l*128
                                                float* __restrict__ hout,
                                                float* __restrict__ sums,       // [G,384]
                                                int layer, int N) {
  int wid = (blockIdx.x * blockDim.x + threadIdx.x) >> 6;  // node id
  if (wid >= N) return;
  int lane = threadIdx.x & 63;
  int f = lane * 2;
  int e0 = rowstart[wid];
  int e1 = rowstart[wid + 1];
  float di = dis[wid];

  float2 self = *(const float2*)(xs + (size_t)wid * FEAT + f);
  float ax = self.x;
  float ay = self.y;
  int e = e0;
  for (; e + 1 < e1; e += 2) {
    int s0 = csrc[e];
    int s1 = csrc[e + 1];
    float2 v0 = *(const float2*)(xs + (size_t)s0 * FEAT + f);
    float2 v1 = *(const float2*)(xs + (size_t)s1 * FEAT + f);
    ax += v0.x + v1.x;
    ay += v0.y + v1.y;
  }
  if (e < e1) {
    int s = csrc[e];
    float2 v = *(const float2*)(xs + (size_t)s * FEAT + f);
    ax += v.x;
    ay += v.y;
  }
  ax *= di;
  ay *= di;
  float rx = fmaxf(ax * bns[f] + bnt[f], 0.f);
  float ry = fmaxf(ay * bns[f + 1] + bnt[f + 1], 0.f);
  *(float2*)(hout + (size_t)wid * FEAT + f) = make_float2(rx, ry);

  // fused global-mean-pool accumulation (counts handled in head_k)
  int g = batch[wid];
  float* sp = sums + (size_t)g * (NLAYERS * FEAT) + layer * FEAT + f;
  atomicAdd(sp, rx);
  atomicAdd(sp + 1, ry);
}

// ---------------------------------------------------------------------------
// Head: pooled = sums/cnt; z1 = relu(pooled@W1+b1); z2 = z1@W2+b2; log_softmax.
// grid G blocks, 128 threads.
// ---------------------------------------------------------------------------
__global__ __launch_bounds__(128) void head_k(const float* __restrict__ sums,
                                              const int* __restrict__ gstart,
                                              const float* __restrict__ W1,
                                              const float* __restrict__ b1,
                                              const float* __restrict__ W2,
                                              const float* __restrict__ b2,
                                              float* __restrict__ out) {
  __shared__ float pooled[NLAYERS * FEAT];
  __shared__ float z1[FEAT];
  __shared__ float z2[2];
  int g = blockIdx.x;
  int t = threadIdx.x;
  float cnt = (float)(gstart[g + 1] - gstart[g]);
  float inv = 1.f / fmaxf(cnt, 1.f);
  for (int k = t; k < NLAYERS * FEAT; k += 128) pooled[k] = sums[g * (NLAYERS * FEAT) + k] * inv;
  __syncthreads();
  float acc = b1[t];
  for (int k = 0; k < NLAYERS * FEAT; ++k) acc += pooled[k] * W1[k * FEAT + t];
  z1[t] = fmaxf(acc, 0.f);
  __syncthreads();
  if (t < 2) {
    float a = b2[t];
    for (int j = 0; j < FEAT; ++j) a += z1[j] * W2[j * 2 + t];
    z2[t] = a;
  }
  __syncthreads();
  if (t < 2) {
    float m = fmaxf(z2[0], z2[1]);
    float lse = m + logf(expf(z2[0] - m) + expf(z2[1] - m));
    out[g * 2 + t] = z2[t] - lse;
  }
}

// ---------------------------------------------------------------------------

extern "C" void kernel_launch(void* const* d_in, const int* in_sizes, int n_in,
                              void* d_out, int out_size, void* d_ws, size_t ws_size,
                              hipStream_t stream) {
  const float* x    = (const float*)d_in[0];
  const int*   ei   = (const int*)d_in[1];   // [2, E]
  const int*   batch= (const int*)d_in[2];   // [N]
  const float* Wc   = (const float*)d_in[3]; // [3,2,64,64]
  const float* bc   = (const float*)d_in[4]; // [3,2,64] == [3,128]
  const float* gam  = (const float*)d_in[5];
  const float* bet  = (const float*)d_in[6];
  const float* mu   = (const float*)d_in[7];
  const float* var  = (const float*)d_in[8];
  const float* W1   = (const float*)d_in[9];  // [384,128]
  const float* b1   = (const float*)d_in[10]; // [128]
  const float* W2   = (const float*)d_in[11]; // [128,2]
  const float* b2   = (const float*)d_in[12]; // [2]
  float* out = (float*)d_out;

  const int N = in_sizes[0] / FEAT;
  const int E = in_sizes[1] / 2;
  const int G = out_size / 2;

  const int* row = ei;
  const int* col = ei + E;

  // workspace carve (256B aligned)
  char* p = (char*)d_ws;
  auto alloc = [&](size_t bytes) -> void* {
    void* q = (void*)p;
    p += (bytes + 255) & ~(size_t)255;
    return q;
  };
  int*   hist     = (int*)alloc((size_t)N * 4);
  float* dis      = (float*)alloc((size_t)N * 4);
  int*   rowstart = (int*)alloc((size_t)(N + 1) * 4);
  int*   cursor   = (int*)alloc((size_t)N * 4);
  int*   csrc     = (int*)alloc((size_t)E * 4);
  int*   bsum     = (int*)alloc(1024 * 4);
  int*   gstart   = (int*)alloc(1024 * 4);
  float* bns      = (float*)alloc(NLAYERS * FEAT * 4);
  float* bnt      = (float*)alloc(NLAYERS * FEAT * 4);
  float* sums     = (float*)alloc((size_t)G * NLAYERS * FEAT * 4);
  float* bufA     = (float*)alloc((size_t)N * FEAT * 4);  // xs (pre-scaled xw)
  float* bufB     = (float*)alloc((size_t)N * FEAT * 4);  // h (post act)

  const int nbN = (N + 255) / 256;
  const int nbE = (E + 255) / 256;

  // CSR build
  hipMemsetAsync(hist, 0, (size_t)N * 4, stream);
  hipMemsetAsync(sums, 0, (size_t)G * NLAYERS * FEAT * 4, stream);
  hist_k<<<nbE, 256, 0, stream>>>(col, hist, E);
  scan1<<<nbN, 256, 0, stream>>>(hist, bsum, N);
  scan2<<<1, 512, 0, stream>>>(bsum, nbN);
  scan3<<<nbN, 256, 0, stream>>>(hist, bsum, rowstart, cursor, dis, N, E);
  fill_k<<<nbE, 256, 0, stream>>>(row, col, cursor, csrc, E);

  // graph boundaries + fused BN params
  boundaries_k<<<nbN, 256, 0, stream>>>(batch, gstart, N, G);
  bnprep_k<<<NLAYERS, FEAT, 0, stream>>>(bc, gam, bet, mu, var, bns, bnt);

  // layers (pooling fused into gather_k)
  const int xwBlocks = (N + 63) / 64;
  const int gaBlocks = (N + 3) / 4;
  const float* hin = x;
  for (int l = 0; l < NLAYERS; ++l) {
    xw_k<<<xwBlocks, 256, 0, stream>>>(hin, Wc + (size_t)l * 8192, dis, bufA, N);
    gather_k<<<gaBlocks, 256, 0, stream>>>(bufA, dis, rowstart, csrc, batch,
                                           bns + l * FEAT, bnt + l * FEAT,
                                           bufB, sums, l, N);
    hin = bufB;
  }

  head_k<<<G, 128, 0, stream>>>(sums, gstart, W1, b1, W2, b2, out);
}

// Round 3
// 2098.101 us; speedup vs baseline: 1.2931x; 1.1310x over previous
//
#include <hip/hip_runtime.h>
#include <cstdint>
#include <cstddef>

// Problem constants (match reference)
#define FEAT 128          // IN_DIM == HID
#define NLAYERS 3
#define EPS 1e-5f

typedef unsigned int uint32;

// pack two fp32 -> bf16 pair (RNE), low = even feature, high = odd feature
__device__ __forceinline__ uint32 pack_bf16(float a, float b) {
  uint32 ua = __float_as_uint(a);
  uint32 ub = __float_as_uint(b);
  ua += 0x7fffu + ((ua >> 16) & 1u);
  ub += 0x7fffu + ((ub >> 16) & 1u);
  return (ua >> 16) | (ub & 0xffff0000u);
}

// ---------------------------------------------------------------------------
// CSR build: in-degree histogram -> exclusive scan -> fill (by target node)
// ---------------------------------------------------------------------------

__global__ void hist_k(const int* __restrict__ col, int* __restrict__ hist, int E) {
  int e = blockIdx.x * blockDim.x + threadIdx.x;
  if (e < E) atomicAdd(&hist[col[e]], 1);
}

__global__ void scan1(const int* __restrict__ hist, int* __restrict__ bsum, int N) {
  __shared__ int s[256];
  int t = threadIdx.x;
  int n = blockIdx.x * 256 + t;
  s[t] = (n < N) ? hist[n] : 0;
  __syncthreads();
  for (int o = 128; o > 0; o >>= 1) {
    if (t < o) s[t] += s[t + o];
    __syncthreads();
  }
  if (t == 0) bsum[blockIdx.x] = s[0];
}

__global__ void scan2(int* __restrict__ bsum, int nb) {
  // single block, blockDim = 512, nb <= 512
  __shared__ int s[512];
  int t = threadIdx.x;
  int v = (t < nb) ? bsum[t] : 0;
  s[t] = v;
  __syncthreads();
  for (int o = 1; o < 512; o <<= 1) {
    int add = (t >= o) ? s[t - o] : 0;
    __syncthreads();
    s[t] += add;
    __syncthreads();
  }
  if (t < nb) bsum[t] = s[t] - v;  // exclusive
}

__global__ void scan3(const int* __restrict__ hist, const int* __restrict__ bsum,
                      int* __restrict__ rowstart, int* __restrict__ cursor,
                      float* __restrict__ dis, int N, int E) {
  __shared__ int s[256];
  int t = threadIdx.x;
  int n = blockIdx.x * 256 + t;
  int v = (n < N) ? hist[n] : 0;
  s[t] = v;
  __syncthreads();
  for (int o = 1; o < 256; o <<= 1) {
    int add = (t >= o) ? s[t - o] : 0;
    __syncthreads();
    s[t] += add;
    __syncthreads();
  }
  if (n < N) {
    int excl = bsum[blockIdx.x] + s[t] - v;
    rowstart[n] = excl;
    cursor[n] = excl;
    // deg = in-degree + 1 (self loop); dis = rsqrt(deg)
    dis[n] = rsqrtf((float)(v + 1));
    if (n == N - 1) rowstart[N] = E;
  }
}

__global__ void fill_k(const int* __restrict__ row, const int* __restrict__ col,
                       int* __restrict__ cursor, int* __restrict__ csrc, int E) {
  int e = blockIdx.x * blockDim.x + threadIdx.x;
  if (e >= E) return;
  int c = col[e];
  int pos = atomicAdd(&cursor[c], 1);
  csrc[pos] = row[e];
}

// ---------------------------------------------------------------------------
// Graph boundaries from sorted batch vector (start[g] per graph, start[G]=N)
// ---------------------------------------------------------------------------
__global__ void boundaries_k(const int* __restrict__ batch, int* __restrict__ gstart,
                             int N, int G) {
  int n = blockIdx.x * blockDim.x + threadIdx.x;
  if (n >= N) return;
  int b = batch[n];
  int prev = (n == 0) ? -1 : batch[n - 1];
  for (int g = prev + 1; g <= b; ++g) gstart[g] = n;
  if (n == N - 1) {
    for (int g = b + 1; g <= G; ++g) gstart[g] = N;
  }
}

// ---------------------------------------------------------------------------
// Precompute fused BN affine per layer: y = s*x + t  where x = agg (pre-bias)
// ---------------------------------------------------------------------------
__global__ void bnprep_k(const float* __restrict__ bconv, const float* __restrict__ gamma,
                         const float* __restrict__ beta, const float* __restrict__ mean,
                         const float* __restrict__ var, float* __restrict__ bns,
                         float* __restrict__ bnt) {
  int l = blockIdx.x;
  int f = threadIdx.x;
  int i = l * FEAT + f;
  float s = gamma[i] * rsqrtf(var[i] + EPS);
  bns[i] = s;
  bnt[i] = (bconv[i] - mean[i]) * s + beta[i];
}

// ---------------------------------------------------------------------------
// xs = bf16( dis[n] * (h @ blockdiag(W[l,0], W[l,1])) ), packed 2 feats/uint.
// Tile: 64 nodes x 128 outputs per block (256 thr), 4x4 register tile/thread.
// ---------------------------------------------------------------------------
__global__ __launch_bounds__(256) void xw_k(const float* __restrict__ h,
                                            const float* __restrict__ W,  // + l*8192
                                            const float* __restrict__ dis,
                                            uint32* __restrict__ xsb, int N) {
  __shared__ float hT[64 * 68];  // [k][n], row stride 68 floats (272B, 16B-aligned)
  __shared__ float Ws[64 * 64];  // [k][j]
  const int t = threadIdx.x;
  const int a = t >> 4;   // node-quad 0..15
  const int b = t & 15;   // out-quad  0..15
  const int base = blockIdx.x * 64;

  for (int p = 0; p < 2; ++p) {
    // stage W[p] (4096 floats, contiguous)
    {
      const float4* src = (const float4*)(W + p * 4096);
      float4* dst = (float4*)Ws;
#pragma unroll
      for (int r = 0; r < 4; ++r) dst[r * 256 + t] = src[r * 256 + t];
    }
    // stage h tile transposed: hT[k][n] = h[base+n][p*64+k]
#pragma unroll
    for (int r = 0; r < 4; ++r) {
      int qid = r * 256 + t;   // 0..1023
      int n = qid >> 4;        // 0..63
      int q = qid & 15;        // k-quad
      float4 v = make_float4(0.f, 0.f, 0.f, 0.f);
      int node = base + n;
      if (node < N) v = *(const float4*)(h + (size_t)node * FEAT + p * 64 + q * 4);
      hT[(q * 4 + 0) * 68 + n] = v.x;
      hT[(q * 4 + 1) * 68 + n] = v.y;
      hT[(q * 4 + 2) * 68 + n] = v.z;
      hT[(q * 4 + 3) * 68 + n] = v.w;
    }
    __syncthreads();

    float acc[4][4];
#pragma unroll
    for (int i = 0; i < 4; ++i)
#pragma unroll
      for (int j = 0; j < 4; ++j) acc[i][j] = 0.f;

#pragma unroll 8
    for (int k = 0; k < 64; ++k) {
      float4 hv = *(const float4*)(hT + k * 68 + a * 4);
      float4 wv = *(const float4*)(Ws + k * 64 + b * 4);
      acc[0][0] += hv.x * wv.x; acc[0][1] += hv.x * wv.y; acc[0][2] += hv.x * wv.z; acc[0][3] += hv.x * wv.w;
      acc[1][0] += hv.y * wv.x; acc[1][1] += hv.y * wv.y; acc[1][2] += hv.y * wv.z; acc[1][3] += hv.y * wv.w;
      acc[2][0] += hv.z * wv.x; acc[2][1] += hv.z * wv.y; acc[2][2] += hv.z * wv.z; acc[2][3] += hv.z * wv.w;
      acc[3][0] += hv.w * wv.x; acc[3][1] += hv.w * wv.y; acc[3][2] += hv.w * wv.z; acc[3][3] += hv.w * wv.w;
    }

#pragma unroll
    for (int i = 0; i < 4; ++i) {
      int node = base + a * 4 + i;
      if (node < N) {
        float d = dis[node];
        uint2 w;
        w.x = pack_bf16(acc[i][0] * d, acc[i][1] * d);
        w.y = pack_bf16(acc[i][2] * d, acc[i][3] * d);
        *(uint2*)(xsb + (size_t)node * 64 + p * 32 + b * 2) = w;
      }
    }
    __syncthreads();
  }
}

// ---------------------------------------------------------------------------
// Gather + self-loop + BN/ReLU + pooled-sum fused. One wave per node; lane
// holds feature pair (2*lane, 2*lane+1) as a packed bf16 uint (256B/row).
// Edge sources are batch-preloaded into a register (csrc[e0+lane]) and
// broadcast via __shfl, so gather loads have no load->load dependency.
//   agg[i] = dis[i] * ( sum_{in-edges} xs[src] + xs[i] )     (xs pre-scaled)
//   h_out  = relu(agg*s + t);  sums[batch[i]] += h_out
// ---------------------------------------------------------------------------
__global__ __launch_bounds__(256) void gather_k(const uint32* __restrict__ xsb,
                                                const float* __restrict__ dis,
                                                const int* __restrict__ rowstart,
                                                const int* __restrict__ csrc,
                                                const int* __restrict__ batch,
                                                const float* __restrict__ bns,  // + l*128
                                                const float* __restrict__ bnt,  // + l*128
                                                float* __restrict__ hout,
                                                float* __restrict__ sums,       // [G,384]
                                                int layer, int N) {
  int wid = (blockIdx.x * blockDim.x + threadIdx.x) >> 6;  // node id
  if (wid >= N) return;
  int lane = threadIdx.x & 63;
  int f = lane * 2;
  int e0 = rowstart[wid];
  int e1 = rowstart[wid + 1];
  float di = dis[wid];

  uint32 self = xsb[(size_t)wid * 64 + lane];
  float ax = __uint_as_float(self << 16);
  float ay = __uint_as_float(self & 0xffff0000u);

  for (int base = e0; base < e1; base += 64) {
    int cnt = min(64, e1 - base);
    int my = (lane < cnt) ? csrc[base + lane] : 0;
    int j = 0;
    for (; j + 3 < cnt; j += 4) {
      int s0 = __shfl(my, j);
      int s1 = __shfl(my, j + 1);
      int s2 = __shfl(my, j + 2);
      int s3 = __shfl(my, j + 3);
      uint32 v0 = xsb[(size_t)s0 * 64 + lane];
      uint32 v1 = xsb[(size_t)s1 * 64 + lane];
      uint32 v2 = xsb[(size_t)s2 * 64 + lane];
      uint32 v3 = xsb[(size_t)s3 * 64 + lane];
      ax += __uint_as_float(v0 << 16);
      ay += __uint_as_float(v0 & 0xffff0000u);
      ax += __uint_as_float(v1 << 16);
      ay += __uint_as_float(v1 & 0xffff0000u);
      ax += __uint_as_float(v2 << 16);
      ay += __uint_as_float(v2 & 0xffff0000u);
      ax += __uint_as_float(v3 << 16);
      ay += __uint_as_float(v3 & 0xffff0000u);
    }
    for (; j < cnt; ++j) {
      int s = __shfl(my, j);
      uint32 v = xsb[(size_t)s * 64 + lane];
      ax += __uint_as_float(v << 16);
      ay += __uint_as_float(v & 0xffff0000u);
    }
  }
  ax *= di;
  ay *= di;
  float rx = fmaxf(ax * bns[f] + bnt[f], 0.f);
  float ry = fmaxf(ay * bns[f + 1] + bnt[f + 1], 0.f);
  *(float2*)(hout + (size_t)wid * FEAT + f) = make_float2(rx, ry);

  // fused global-mean-pool accumulation (counts handled in head_k)
  int g = batch[wid];
  float* sp = sums + (size_t)g * (NLAYERS * FEAT) + layer * FEAT + f;
  atomicAdd(sp, rx);
  atomicAdd(sp + 1, ry);
}

// ---------------------------------------------------------------------------
// Head: pooled = sums/cnt; z1 = relu(pooled@W1+b1); z2 = z1@W2+b2; log_softmax.
// ---------------------------------------------------------------------------
__global__ __launch_bounds__(128) void head_k(const float* __restrict__ sums,
                                              const int* __restrict__ gstart,
                                              const float* __restrict__ W1,
                                              const float* __restrict__ b1,
                                              const float* __restrict__ W2,
                                              const float* __restrict__ b2,
                                              float* __restrict__ out) {
  __shared__ float pooled[NLAYERS * FEAT];
  __shared__ float z1[FEAT];
  __shared__ float z2[2];
  int g = blockIdx.x;
  int t = threadIdx.x;
  float cnt = (float)(gstart[g + 1] - gstart[g]);
  float inv = 1.f / fmaxf(cnt, 1.f);
  for (int k = t; k < NLAYERS * FEAT; k += 128) pooled[k] = sums[g * (NLAYERS * FEAT) + k] * inv;
  __syncthreads();
  float acc = b1[t];
  for (int k = 0; k < NLAYERS * FEAT; ++k) acc += pooled[k] * W1[k * FEAT + t];
  z1[t] = fmaxf(acc, 0.f);
  __syncthreads();
  if (t < 2) {
    float a = b2[t];
    for (int j = 0; j < FEAT; ++j) a += z1[j] * W2[j * 2 + t];
    z2[t] = a;
  }
  __syncthreads();
  if (t < 2) {
    float m = fmaxf(z2[0], z2[1]);
    float lse = m + logf(expf(z2[0] - m) + expf(z2[1] - m));
    out[g * 2 + t] = z2[t] - lse;
  }
}

// ---------------------------------------------------------------------------

extern "C" void kernel_launch(void* const* d_in, const int* in_sizes, int n_in,
                              void* d_out, int out_size, void* d_ws, size_t ws_size,
                              hipStream_t stream) {
  const float* x    = (const float*)d_in[0];
  const int*   ei   = (const int*)d_in[1];   // [2, E]
  const int*   batch= (const int*)d_in[2];   // [N]
  const float* Wc   = (const float*)d_in[3]; // [3,2,64,64]
  const float* bc   = (const float*)d_in[4]; // [3,2,64] == [3,128]
  const float* gam  = (const float*)d_in[5];
  const float* bet  = (const float*)d_in[6];
  const float* mu   = (const float*)d_in[7];
  const float* var  = (const float*)d_in[8];
  const float* W1   = (const float*)d_in[9];  // [384,128]
  const float* b1   = (const float*)d_in[10]; // [128]
  const float* W2   = (const float*)d_in[11]; // [128,2]
  const float* b2   = (const float*)d_in[12]; // [2]
  float* out = (float*)d_out;

  const int N = in_sizes[0] / FEAT;
  const int E = in_sizes[1] / 2;
  const int G = out_size / 2;

  const int* row = ei;
  const int* col = ei + E;

  // workspace carve (256B aligned)
  char* p = (char*)d_ws;
  auto alloc = [&](size_t bytes) -> void* {
    void* q = (void*)p;
    p += (bytes + 255) & ~(size_t)255;
    return q;
  };
  int*    hist     = (int*)alloc((size_t)N * 4);
  float*  dis      = (float*)alloc((size_t)N * 4);
  int*    rowstart = (int*)alloc((size_t)(N + 1) * 4);
  int*    cursor   = (int*)alloc((size_t)N * 4);
  int*    csrc     = (int*)alloc((size_t)E * 4);
  int*    bsum     = (int*)alloc(1024 * 4);
  int*    gstart   = (int*)alloc(1024 * 4);
  float*  bns      = (float*)alloc(NLAYERS * FEAT * 4);
  float*  bnt      = (float*)alloc(NLAYERS * FEAT * 4);
  float*  sums     = (float*)alloc((size_t)G * NLAYERS * FEAT * 4);
  uint32* bufA     = (uint32*)alloc((size_t)N * 64 * 4);  // xs bf16-packed
  float*  bufB     = (float*)alloc((size_t)N * FEAT * 4); // h (post act)

  const int nbN = (N + 255) / 256;
  const int nbE = (E + 255) / 256;

  // CSR build
  hipMemsetAsync(hist, 0, (size_t)N * 4, stream);
  hipMemsetAsync(sums, 0, (size_t)G * NLAYERS * FEAT * 4, stream);
  hist_k<<<nbE, 256, 0, stream>>>(col, hist, E);
  scan1<<<nbN, 256, 0, stream>>>(hist, bsum, N);
  scan2<<<1, 512, 0, stream>>>(bsum, nbN);
  scan3<<<nbN, 256, 0, stream>>>(hist, bsum, rowstart, cursor, dis, N, E);
  fill_k<<<nbE, 256, 0, stream>>>(row, col, cursor, csrc, E);

  // graph boundaries + fused BN params
  boundaries_k<<<nbN, 256, 0, stream>>>(batch, gstart, N, G);
  bnprep_k<<<NLAYERS, FEAT, 0, stream>>>(bc, gam, bet, mu, var, bns, bnt);

  // layers (pooling fused into gather_k)
  const int xwBlocks = (N + 63) / 64;
  const int gaBlocks = (N + 3) / 4;
  const float* hin = x;
  for (int l = 0; l < NLAYERS; ++l) {
    xw_k<<<xwBlocks, 256, 0, stream>>>(hin, Wc + (size_t)l * 8192, dis, bufA, N);
    gather_k<<<gaBlocks, 256, 0, stream>>>(bufA, dis, rowstart, csrc, batch,
                                           bns + l * FEAT, bnt + l * FEAT,
                                           bufB, sums, l, N);
    hin = bufB;
  }

  head_k<<<G, 128, 0, stream>>>(sums, gstart, W1, b1, W2, b2, out);
}

// Round 4
// 955.847 us; speedup vs baseline: 2.8384x; 2.1950x over previous
//
#include <hip/hip_runtime.h>
#include <cstdint>
#include <cstddef>

// Problem constants (match reference)
#define FEAT 128          // IN_DIM == HID
#define NLAYERS 3
#define EPS 1e-5f

typedef unsigned int uint32;
typedef float floatx2 __attribute__((ext_vector_type(2)));

// ---------------------------------------------------------------------------
// CSR build: in-degree histogram -> exclusive scan -> fill (by target node)
// ---------------------------------------------------------------------------

__global__ void hist_k(const int* __restrict__ col, int* __restrict__ hist, int E) {
  int e = blockIdx.x * blockDim.x + threadIdx.x;
  if (e < E) atomicAdd(&hist[col[e]], 1);
}

__global__ void scan1(const int* __restrict__ hist, int* __restrict__ bsum, int N) {
  __shared__ int s[256];
  int t = threadIdx.x;
  int n = blockIdx.x * 256 + t;
  s[t] = (n < N) ? hist[n] : 0;
  __syncthreads();
  for (int o = 128; o > 0; o >>= 1) {
    if (t < o) s[t] += s[t + o];
    __syncthreads();
  }
  if (t == 0) bsum[blockIdx.x] = s[0];
}

__global__ void scan2(int* __restrict__ bsum, int nb) {
  // single block, blockDim = 512, nb <= 512
  __shared__ int s[512];
  int t = threadIdx.x;
  int v = (t < nb) ? bsum[t] : 0;
  s[t] = v;
  __syncthreads();
  for (int o = 1; o < 512; o <<= 1) {
    int add = (t >= o) ? s[t - o] : 0;
    __syncthreads();
    s[t] += add;
    __syncthreads();
  }
  if (t < nb) bsum[t] = s[t] - v;  // exclusive
}

__global__ void scan3(const int* __restrict__ hist, const int* __restrict__ bsum,
                      int* __restrict__ rowstart, int* __restrict__ cursor,
                      float* __restrict__ dis, int N, int E) {
  __shared__ int s[256];
  int t = threadIdx.x;
  int n = blockIdx.x * 256 + t;
  int v = (n < N) ? hist[n] : 0;
  s[t] = v;
  __syncthreads();
  for (int o = 1; o < 256; o <<= 1) {
    int add = (t >= o) ? s[t - o] : 0;
    __syncthreads();
    s[t] += add;
    __syncthreads();
  }
  if (n < N) {
    int excl = bsum[blockIdx.x] + s[t] - v;
    rowstart[n] = excl;
    cursor[n] = excl;
    // deg = in-degree + 1 (self loop); dis = rsqrt(deg)
    dis[n] = rsqrtf((float)(v + 1));
    if (n == N - 1) rowstart[N] = E;
  }
}

__global__ void fill_k(const int* __restrict__ row, const int* __restrict__ col,
                       int* __restrict__ cursor, int* __restrict__ csrc, int E) {
  int e = blockIdx.x * blockDim.x + threadIdx.x;
  if (e >= E) return;
  int c = col[e];
  int pos = atomicAdd(&cursor[c], 1);
  csrc[pos] = row[e];
}

// ---------------------------------------------------------------------------
// Graph boundaries from sorted batch vector (start[g] per graph, start[G]=N)
// ---------------------------------------------------------------------------
__global__ void boundaries_k(const int* __restrict__ batch, int* __restrict__ gstart,
                             int N, int G) {
  int n = blockIdx.x * blockDim.x + threadIdx.x;
  if (n >= N) return;
  int b = batch[n];
  int prev = (n == 0) ? -1 : batch[n - 1];
  for (int g = prev + 1; g <= b; ++g) gstart[g] = n;
  if (n == N - 1) {
    for (int g = b + 1; g <= G; ++g) gstart[g] = N;
  }
}

// ---------------------------------------------------------------------------
// Precompute fused BN affine per layer: y = s*x + t  where x = agg (pre-bias)
// ---------------------------------------------------------------------------
__global__ void bnprep_k(const float* __restrict__ bconv, const float* __restrict__ gamma,
                         const float* __restrict__ beta, const float* __restrict__ mean,
                         const float* __restrict__ var, float* __restrict__ bns,
                         float* __restrict__ bnt) {
  int l = blockIdx.x;
  int f = threadIdx.x;
  int i = l * FEAT + f;
  float s = gamma[i] * rsqrtf(var[i] + EPS);
  bns[i] = s;
  bnt[i] = (bconv[i] - mean[i]) * s + beta[i];
}

// ---------------------------------------------------------------------------
// xs = fp8_e4m3( dis[n] * (h @ blockdiag(W[l,0], W[l,1])) ), 1 byte/feature,
// row = 128 B (2 cache lines) -> halves the line-fill cost of the gather.
// Tile: 64 nodes x 128 outputs per block (256 thr), 4x4 register tile/thread.
// ---------------------------------------------------------------------------
__global__ __launch_bounds__(256) void xw_k(const float* __restrict__ h,
                                            const float* __restrict__ W,  // + l*8192
                                            const float* __restrict__ dis,
                                            uint32* __restrict__ xs8, int N) {
  __shared__ float hT[64 * 68];  // [k][n], row stride 68 floats (272B, 16B-aligned)
  __shared__ float Ws[64 * 64];  // [k][j]
  const int t = threadIdx.x;
  const int a = t >> 4;   // node-quad 0..15
  const int b = t & 15;   // out-quad  0..15
  const int base = blockIdx.x * 64;

  for (int p = 0; p < 2; ++p) {
    // stage W[p] (4096 floats, contiguous)
    {
      const float4* src = (const float4*)(W + p * 4096);
      float4* dst = (float4*)Ws;
#pragma unroll
      for (int r = 0; r < 4; ++r) dst[r * 256 + t] = src[r * 256 + t];
    }
    // stage h tile transposed: hT[k][n] = h[base+n][p*64+k]
#pragma unroll
    for (int r = 0; r < 4; ++r) {
      int qid = r * 256 + t;   // 0..1023
      int n = qid >> 4;        // 0..63
      int q = qid & 15;        // k-quad
      float4 v = make_float4(0.f, 0.f, 0.f, 0.f);
      int node = base + n;
      if (node < N) v = *(const float4*)(h + (size_t)node * FEAT + p * 64 + q * 4);
      hT[(q * 4 + 0) * 68 + n] = v.x;
      hT[(q * 4 + 1) * 68 + n] = v.y;
      hT[(q * 4 + 2) * 68 + n] = v.z;
      hT[(q * 4 + 3) * 68 + n] = v.w;
    }
    __syncthreads();

    float acc[4][4];
#pragma unroll
    for (int i = 0; i < 4; ++i)
#pragma unroll
      for (int j = 0; j < 4; ++j) acc[i][j] = 0.f;

#pragma unroll 8
    for (int k = 0; k < 64; ++k) {
      float4 hv = *(const float4*)(hT + k * 68 + a * 4);
      float4 wv = *(const float4*)(Ws + k * 64 + b * 4);
      acc[0][0] += hv.x * wv.x; acc[0][1] += hv.x * wv.y; acc[0][2] += hv.x * wv.z; acc[0][3] += hv.x * wv.w;
      acc[1][0] += hv.y * wv.x; acc[1][1] += hv.y * wv.y; acc[1][2] += hv.y * wv.z; acc[1][3] += hv.y * wv.w;
      acc[2][0] += hv.z * wv.x; acc[2][1] += hv.z * wv.y; acc[2][2] += hv.z * wv.z; acc[2][3] += hv.z * wv.w;
      acc[3][0] += hv.w * wv.x; acc[3][1] += hv.w * wv.y; acc[3][2] += hv.w * wv.z; acc[3][3] += hv.w * wv.w;
    }

#pragma unroll
    for (int i = 0; i < 4; ++i) {
      int node = base + a * 4 + i;
      if (node < N) {
        float d = dis[node];
        int w = __builtin_amdgcn_cvt_pk_fp8_f32(acc[i][0] * d, acc[i][1] * d, 0, false);
        w = __builtin_amdgcn_cvt_pk_fp8_f32(acc[i][2] * d, acc[i][3] * d, w, true);
        xs8[(size_t)node * 32 + p * 16 + b] = (uint32)w;
      }
    }
    __syncthreads();
  }
}

// ---------------------------------------------------------------------------
// Gather + self-loop + BN/ReLU + pooled-sum fused. One wave per node; lane
// holds feature pair (2*lane, 2*lane+1) as packed fp8x2 ushort (128B/row).
// Edge sources batch-preloaded (csrc[e0+lane]) and broadcast via __shfl:
// gather loads carry no load->load dependency; unroll 8 keeps 8 in flight.
//   agg[i] = dis[i] * ( sum_{in-edges} xs[src] + xs[i] )     (xs pre-scaled)
//   h_out  = relu(agg*s + t);  sums[batch[i]] += h_out (LDS-reduced x4)
// ---------------------------------------------------------------------------
__global__ __launch_bounds__(256) void gather_k(const unsigned short* __restrict__ xs8,
                                                const float* __restrict__ dis,
                                                const int* __restrict__ rowstart,
                                                const int* __restrict__ csrc,
                                                const int* __restrict__ batch,
                                                const float* __restrict__ bns,  // + l*128
                                                const float* __restrict__ bnt,  // + l*128
                                                float* __restrict__ hout,
                                                float* __restrict__ sums,       // [G,384]
                                                int layer, int N) {
  const int w = threadIdx.x >> 6;
  const int lane = threadIdx.x & 63;
  const int wid = blockIdx.x * 4 + w;
  const bool valid = (wid < N);
  const int f = lane * 2;

  float rx = 0.f, ry = 0.f;
  int g = -1;

  if (valid) {
    int e0 = rowstart[wid];
    int e1 = rowstart[wid + 1];
    float di = dis[wid];

    int selfv = xs8[(size_t)wid * 64 + lane];
    floatx2 sc = __builtin_amdgcn_cvt_pk_f32_fp8(selfv, false);
    float ax = sc[0];
    float ay = sc[1];

    for (int base = e0; base < e1; base += 64) {
      int cnt = min(64, e1 - base);
      int my = (lane < cnt) ? csrc[base + lane] : 0;
      int j = 0;
      for (; j + 7 < cnt; j += 8) {
        int s0 = __shfl(my, j);
        int s1 = __shfl(my, j + 1);
        int s2 = __shfl(my, j + 2);
        int s3 = __shfl(my, j + 3);
        int s4 = __shfl(my, j + 4);
        int s5 = __shfl(my, j + 5);
        int s6 = __shfl(my, j + 6);
        int s7 = __shfl(my, j + 7);
        int v0 = xs8[(size_t)s0 * 64 + lane];
        int v1 = xs8[(size_t)s1 * 64 + lane];
        int v2 = xs8[(size_t)s2 * 64 + lane];
        int v3 = xs8[(size_t)s3 * 64 + lane];
        int v4 = xs8[(size_t)s4 * 64 + lane];
        int v5 = xs8[(size_t)s5 * 64 + lane];
        int v6 = xs8[(size_t)s6 * 64 + lane];
        int v7 = xs8[(size_t)s7 * 64 + lane];
        floatx2 c0 = __builtin_amdgcn_cvt_pk_f32_fp8(v0, false);
        floatx2 c1 = __builtin_amdgcn_cvt_pk_f32_fp8(v1, false);
        floatx2 c2 = __builtin_amdgcn_cvt_pk_f32_fp8(v2, false);
        floatx2 c3 = __builtin_amdgcn_cvt_pk_f32_fp8(v3, false);
        floatx2 c4 = __builtin_amdgcn_cvt_pk_f32_fp8(v4, false);
        floatx2 c5 = __builtin_amdgcn_cvt_pk_f32_fp8(v5, false);
        floatx2 c6 = __builtin_amdgcn_cvt_pk_f32_fp8(v6, false);
        floatx2 c7 = __builtin_amdgcn_cvt_pk_f32_fp8(v7, false);
        ax += c0[0] + c1[0] + c2[0] + c3[0] + c4[0] + c5[0] + c6[0] + c7[0];
        ay += c0[1] + c1[1] + c2[1] + c3[1] + c4[1] + c5[1] + c6[1] + c7[1];
      }
      for (; j < cnt; ++j) {
        int s = __shfl(my, j);
        int v = xs8[(size_t)s * 64 + lane];
        floatx2 c = __builtin_amdgcn_cvt_pk_f32_fp8(v, false);
        ax += c[0];
        ay += c[1];
      }
    }
    ax *= di;
    ay *= di;
    rx = fmaxf(ax * bns[f] + bnt[f], 0.f);
    ry = fmaxf(ay * bns[f + 1] + bnt[f + 1], 0.f);
    *(float2*)(hout + (size_t)wid * FEAT + f) = make_float2(rx, ry);
    g = batch[wid];
  }

  // pooled-sum: reduce the block's 4 waves in LDS, 1 atomic per feature if
  // all 4 nodes belong to the same graph (true except at graph boundaries)
  __shared__ float ps[4][FEAT];
  __shared__ int gs[4];
  if (lane == 0) gs[w] = g;
  *(float2*)&ps[w][f] = make_float2(rx, ry);
  __syncthreads();
  if (gs[0] >= 0 && gs[0] == gs[1] && gs[1] == gs[2] && gs[2] == gs[3]) {
    int t = threadIdx.x;
    if (t < FEAT) {
      float s = ps[0][t] + ps[1][t] + ps[2][t] + ps[3][t];
      atomicAdd(&sums[(size_t)gs[0] * (NLAYERS * FEAT) + layer * FEAT + t], s);
    }
  } else if (valid) {
    float* sp = sums + (size_t)g * (NLAYERS * FEAT) + layer * FEAT + f;
    atomicAdd(sp, rx);
    atomicAdd(sp + 1, ry);
  }
}

// ---------------------------------------------------------------------------
// Head: pooled = sums/cnt; z1 = relu(pooled@W1+b1); z2 = z1@W2+b2; log_softmax.
// ---------------------------------------------------------------------------
__global__ __launch_bounds__(128) void head_k(const float* __restrict__ sums,
                                              const int* __restrict__ gstart,
                                              const float* __restrict__ W1,
                                              const float* __restrict__ b1,
                                              const float* __restrict__ W2,
                                              const float* __restrict__ b2,
                                              float* __restrict__ out) {
  __shared__ float pooled[NLAYERS * FEAT];
  __shared__ float z1[FEAT];
  __shared__ float z2[2];
  int g = blockIdx.x;
  int t = threadIdx.x;
  float cnt = (float)(gstart[g + 1] - gstart[g]);
  float inv = 1.f / fmaxf(cnt, 1.f);
  for (int k = t; k < NLAYERS * FEAT; k += 128) pooled[k] = sums[g * (NLAYERS * FEAT) + k] * inv;
  __syncthreads();
  float acc = b1[t];
  for (int k = 0; k < NLAYERS * FEAT; ++k) acc += pooled[k] * W1[k * FEAT + t];
  z1[t] = fmaxf(acc, 0.f);
  __syncthreads();
  if (t < 2) {
    float a = b2[t];
    for (int j = 0; j < FEAT; ++j) a += z1[j] * W2[j * 2 + t];
    z2[t] = a;
  }
  __syncthreads();
  if (t < 2) {
    float m = fmaxf(z2[0], z2[1]);
    float lse = m + logf(expf(z2[0] - m) + expf(z2[1] - m));
    out[g * 2 + t] = z2[t] - lse;
  }
}

// ---------------------------------------------------------------------------

extern "C" void kernel_launch(void* const* d_in, const int* in_sizes, int n_in,
                              void* d_out, int out_size, void* d_ws, size_t ws_size,
                              hipStream_t stream) {
  const float* x    = (const float*)d_in[0];
  const int*   ei   = (const int*)d_in[1];   // [2, E]
  const int*   batch= (const int*)d_in[2];   // [N]
  const float* Wc   = (const float*)d_in[3]; // [3,2,64,64]
  const float* bc   = (const float*)d_in[4]; // [3,2,64] == [3,128]
  const float* gam  = (const float*)d_in[5];
  const float* bet  = (const float*)d_in[6];
  const float* mu   = (const float*)d_in[7];
  const float* var  = (const float*)d_in[8];
  const float* W1   = (const float*)d_in[9];  // [384,128]
  const float* b1   = (const float*)d_in[10]; // [128]
  const float* W2   = (const float*)d_in[11]; // [128,2]
  const float* b2   = (const float*)d_in[12]; // [2]
  float* out = (float*)d_out;

  const int N = in_sizes[0] / FEAT;
  const int E = in_sizes[1] / 2;
  const int G = out_size / 2;

  const int* row = ei;
  const int* col = ei + E;

  // workspace carve (256B aligned)
  char* p = (char*)d_ws;
  auto alloc = [&](size_t bytes) -> void* {
    void* q = (void*)p;
    p += (bytes + 255) & ~(size_t)255;
    return q;
  };
  int*    hist     = (int*)alloc((size_t)N * 4);
  float*  dis      = (float*)alloc((size_t)N * 4);
  int*    rowstart = (int*)alloc((size_t)(N + 1) * 4);
  int*    cursor   = (int*)alloc((size_t)N * 4);
  int*    csrc     = (int*)alloc((size_t)E * 4);
  int*    bsum     = (int*)alloc(1024 * 4);
  int*    gstart   = (int*)alloc(1024 * 4);
  float*  bns      = (float*)alloc(NLAYERS * FEAT * 4);
  float*  bnt      = (float*)alloc(NLAYERS * FEAT * 4);
  float*  sums     = (float*)alloc((size_t)G * NLAYERS * FEAT * 4);
  uint32* bufA     = (uint32*)alloc((size_t)N * FEAT);    // xs fp8-packed (128B/row)
  float*  bufB     = (float*)alloc((size_t)N * FEAT * 4); // h (post act)

  const int nbN = (N + 255) / 256;
  const int nbE = (E + 255) / 256;

  // CSR build
  hipMemsetAsync(hist, 0, (size_t)N * 4, stream);
  hipMemsetAsync(sums, 0, (size_t)G * NLAYERS * FEAT * 4, stream);
  hist_k<<<nbE, 256, 0, stream>>>(col, hist, E);
  scan1<<<nbN, 256, 0, stream>>>(hist, bsum, N);
  scan2<<<1, 512, 0, stream>>>(bsum, nbN);
  scan3<<<nbN, 256, 0, stream>>>(hist, bsum, rowstart, cursor, dis, N, E);
  fill_k<<<nbE, 256, 0, stream>>>(row, col, cursor, csrc, E);

  // graph boundaries + fused BN params
  boundaries_k<<<nbN, 256, 0, stream>>>(batch, gstart, N, G);
  bnprep_k<<<NLAYERS, FEAT, 0, stream>>>(bc, gam, bet, mu, var, bns, bnt);

  // layers (pooling fused into gather_k)
  const int xwBlocks = (N + 63) / 64;
  const int gaBlocks = (N + 3) / 4;
  const float* hin = x;
  for (int l = 0; l < NLAYERS; ++l) {
    xw_k<<<xwBlocks, 256, 0, stream>>>(hin, Wc + (size_t)l * 8192, dis, bufA, N);
    gather_k<<<gaBlocks, 256, 0, stream>>>((const unsigned short*)bufA, dis, rowstart,
                                           csrc, batch, bns + l * FEAT, bnt + l * FEAT,
                                           bufB, sums, l, N);
    hin = bufB;
  }

  head_k<<<G, 128, 0, stream>>>(sums, gstart, W1, b1, W2, b2, out);
}